// Round 1
// baseline (1058.373 us; speedup 1.0000x reference)
//
#include <hip/hip_runtime.h>
#include <cstdint>
#include <cstddef>

typedef unsigned short u16;
typedef short bf16x8 __attribute__((ext_vector_type(8)));
typedef float f32x4 __attribute__((ext_vector_type(4)));

#define AS1C(p) ((const __attribute__((address_space(1))) void*)(p))
#define AS3(p)  ((__attribute__((address_space(3))) void*)(p))
#define MFMA_BF16 __builtin_amdgcn_mfma_f32_16x16x32_bf16

__device__ __forceinline__ u16 f2bf(float f) {
    union { float f; unsigned int u; } v; v.f = f;
    unsigned int r = v.u + 0x7fffu + ((v.u >> 16) & 1u);
    return (u16)(r >> 16);
}

struct U16x4 { u16 x, y, z, w; };

// ---------------- fp32 -> bf16 weight conversion ----------------
__global__ __launch_bounds__(256) void cvt_kernel(const float* __restrict__ src,
                                                  u16* __restrict__ dst, int n4) {
    int i = blockIdx.x * 256 + threadIdx.x;
    if (i < n4) {
        const float4 v = ((const float4*)src)[i];
        U16x4 o; o.x = f2bf(v.x); o.y = f2bf(v.y); o.z = f2bf(v.z); o.w = f2bf(v.w);
        ((U16x4*)dst)[i] = o;
    }
}

// ---------------- RMSNorm (fp32 in, bf16 out), one block per token ----------------
__global__ __launch_bounds__(256) void rmsnorm_kernel(const float* __restrict__ X,
                                                      const float* __restrict__ W,
                                                      u16* __restrict__ Out) {
    const int row = blockIdx.x;
    const int t = threadIdx.x;
    const float* xr = X + (size_t)row * 2048;
    float4 a = ((const float4*)xr)[2 * t];
    float4 b = ((const float4*)xr)[2 * t + 1];
    float ss = a.x*a.x + a.y*a.y + a.z*a.z + a.w*a.w
             + b.x*b.x + b.y*b.y + b.z*b.z + b.w*b.w;
    #pragma unroll
    for (int off = 1; off < 64; off <<= 1) ss += __shfl_xor(ss, off);
    __shared__ float red[4];
    if ((t & 63) == 0) red[t >> 6] = ss;
    __syncthreads();
    float tot = red[0] + red[1] + red[2] + red[3];
    float rs = rsqrtf(tot * (1.0f / 2048.0f) + 1e-5f);
    float vals[8] = {a.x, a.y, a.z, a.w, b.x, b.y, b.z, b.w};
    const int base = t * 8;
    u16* orow = Out + (size_t)row * 2048 + base;
    #pragma unroll
    for (int j = 0; j < 8; ++j) orow[j] = f2bf(vals[j] * rs * W[base + j]);
}

// ---------------- RoPE split: qkv fp32 -> q,k (roped, bf16), v transposed bf16 ----------------
__global__ __launch_bounds__(256) void rope_kernel(const float* __restrict__ qkv,
                                                   const float* __restrict__ fr,
                                                   u16* __restrict__ Qo, u16* __restrict__ Ko,
                                                   u16* __restrict__ Vo) {
    const int tok = blockIdx.x;
    const int b = tok >> 11, s = tok & 2047;
    const int t = threadIdx.x;
    const float* row = qkv + (size_t)tok * 3072;
    const float* f = fr + (size_t)s * 128;
    #pragma unroll
    for (int i = 0; i < 4; ++i) {                 // 1024 q pairs
        int p = t + i * 256;
        int h = p >> 6, pi = p & 63;
        float x0 = row[h * 128 + pi * 2];
        float x1 = row[h * 128 + pi * 2 + 1];
        float c = f[pi * 2], sn = f[pi * 2 + 1];
        size_t ob = ((size_t)(b * 16 + h) * 2048 + s) * 128 + pi * 2;
        Qo[ob]     = f2bf(x0 * c - x1 * sn);
        Qo[ob + 1] = f2bf(x1 * c + x0 * sn);
    }
    {                                             // 256 k pairs
        int kh = t >> 6, pi = t & 63;
        float x0 = row[2048 + kh * 128 + pi * 2];
        float x1 = row[2048 + kh * 128 + pi * 2 + 1];
        float c = f[pi * 2], sn = f[pi * 2 + 1];
        size_t ob = ((size_t)(b * 4 + kh) * 2048 + s) * 128 + pi * 2;
        Ko[ob]     = f2bf(x0 * c - x1 * sn);
        Ko[ob + 1] = f2bf(x1 * c + x0 * sn);
    }
    #pragma unroll
    for (int i = 0; i < 2; ++i) {                 // 512 v elems, transposed (b,kv,d,s)
        int e = t + i * 256;
        int kh = e >> 7, d = e & 127;
        Vo[((size_t)(b * 4 + kh) * 128 + d) * 2048 + s] = f2bf(row[2560 + e]);
    }
}

// ---------------- GEMM: C(M,N) = A(M,K,bf16) * B(N,K,bf16)^T  [m97 structure] ----------------
// RESID: Cf = acc + RES (fp32 out). DUAL: Cb = bf16(silu(acc_B0) * acc_B1).
template <bool RESID, bool DUAL>
__global__ __launch_bounds__(256, 2) void gemm_bt(
    const u16* __restrict__ A, const u16* __restrict__ B0, const u16* __restrict__ B1,
    const float* __restrict__ RES, float* __restrict__ Cf, u16* __restrict__ Cb,
    int M, int N, int K) {
    __shared__ __align__(16) u16 As[128 * 32];
    __shared__ __align__(16) u16 Bs[128 * 32];
    __shared__ __align__(16) u16 Bs2[128 * 32];
    const int w = threadIdx.x >> 6;
    const int lane = threadIdx.x & 63;
    const int bm = blockIdx.y * 128;
    const int bn = blockIdx.x * 128;
    const int wm = (w >> 1) * 64;
    const int wn = (w & 1) * 64;
    const int lr = lane & 15;
    const int kq = (lane >> 4) * 8;
    const int srow = lane >> 2;
    const int skc = (lane & 3) * 8;
    f32x4 acc[4][4];
    f32x4 acc2[4][4];
    const f32x4 z = {0.f, 0.f, 0.f, 0.f};
    #pragma unroll
    for (int i = 0; i < 4; ++i)
        #pragma unroll
        for (int j = 0; j < 4; ++j) { acc[i][j] = z; acc2[i][j] = z; }

    for (int k0 = 0; k0 < K; k0 += 32) {
        #pragma unroll
        for (int c = 0; c < 2; ++c) {
            const int chunk = 2 * w + c;
            const int r = chunk * 16 + srow;
            const int lofs = chunk * 512 + lane * 8;
            __builtin_amdgcn_global_load_lds(AS1C(A + (size_t)(bm + r) * K + k0 + skc),
                                             AS3(&As[lofs]), 16, 0, 0);
            __builtin_amdgcn_global_load_lds(AS1C(B0 + (size_t)(bn + r) * K + k0 + skc),
                                             AS3(&Bs[lofs]), 16, 0, 0);
            if constexpr (DUAL)
                __builtin_amdgcn_global_load_lds(AS1C(B1 + (size_t)(bn + r) * K + k0 + skc),
                                                 AS3(&Bs2[lofs]), 16, 0, 0);
        }
        __syncthreads();
        bf16x8 af[4], bfr[4];
        #pragma unroll
        for (int tm = 0; tm < 4; ++tm) af[tm] = *(const bf16x8*)&As[(wm + tm * 16 + lr) * 32 + kq];
        #pragma unroll
        for (int tn = 0; tn < 4; ++tn) bfr[tn] = *(const bf16x8*)&Bs[(wn + tn * 16 + lr) * 32 + kq];
        #pragma unroll
        for (int tm = 0; tm < 4; ++tm)
            #pragma unroll
            for (int tn = 0; tn < 4; ++tn)
                acc[tm][tn] = MFMA_BF16(af[tm], bfr[tn], acc[tm][tn], 0, 0, 0);
        if constexpr (DUAL) {
            #pragma unroll
            for (int tn = 0; tn < 4; ++tn) bfr[tn] = *(const bf16x8*)&Bs2[(wn + tn * 16 + lr) * 32 + kq];
            #pragma unroll
            for (int tm = 0; tm < 4; ++tm)
                #pragma unroll
                for (int tn = 0; tn < 4; ++tn)
                    acc2[tm][tn] = MFMA_BF16(af[tm], bfr[tn], acc2[tm][tn], 0, 0, 0);
        }
        __syncthreads();
    }
    #pragma unroll
    for (int tm = 0; tm < 4; ++tm) {
        const int row0 = bm + wm + tm * 16 + (lane >> 4) * 4;
        #pragma unroll
        for (int tn = 0; tn < 4; ++tn) {
            const int col = bn + wn + tn * 16 + (lane & 15);
            #pragma unroll
            for (int r = 0; r < 4; ++r) {
                const size_t idx = (size_t)(row0 + r) * N + col;
                if constexpr (DUAL) {
                    float aa = acc[tm][tn][r];
                    float bb = acc2[tm][tn][r];
                    float sg = aa / (1.0f + __expf(-aa));
                    Cb[idx] = f2bf(sg * bb);
                } else {
                    float v = acc[tm][tn][r];
                    if constexpr (RESID) v += RES[idx];
                    Cf[idx] = v;
                }
            }
        }
    }
}

// ---------------- Flash attention: block = (qtile64, head, batch), 4 waves x 16 q-rows ----------------
__global__ __launch_bounds__(256, 2) void attn_kernel(
    const u16* __restrict__ Q, const u16* __restrict__ Kg,
    const u16* __restrict__ Vt, u16* __restrict__ O) {
    __shared__ __align__(16) u16 Ks[32 * 128];   // [kv][d]
    __shared__ __align__(16) u16 Vs[128 * 32];   // [d][kv]
    __shared__ __align__(16) u16 Ps[4][16 * 32]; // per-wave P
    const int qt = blockIdx.x, h = blockIdx.y, b = blockIdx.z;
    const int kvh = h >> 2;
    const int w = threadIdx.x >> 6, lane = threadIdx.x & 63;
    const int q0 = qt * 64;
    const int qw = q0 + w * 16;
    const int lr = lane & 15;
    const int quad = lane >> 4;
    const int srow = lane >> 2, skc = (lane & 3) * 8;
    const u16* qbase = Q + (((size_t)(b * 16 + h) * 2048) + qw + lr) * 128;
    bf16x8 qf[4];
    #pragma unroll
    for (int kk = 0; kk < 4; ++kk) qf[kk] = *(const bf16x8*)(qbase + kk * 32 + quad * 8);
    f32x4 o[8];
    const f32x4 z = {0.f, 0.f, 0.f, 0.f};
    #pragma unroll
    for (int i = 0; i < 8; ++i) o[i] = z;
    float m_r[4] = {-1e30f, -1e30f, -1e30f, -1e30f};
    float l_r[4] = {0.f, 0.f, 0.f, 0.f};
    const float scale = 0.022097086912079608f;   // 1/sqrt(2048)
    const float LOG2E = 1.4426950408889634f;
    const int nkt = (q0 + 64) >> 5;
    const u16* kgbase = Kg + (size_t)(b * 4 + kvh) * 2048 * 128;
    const u16* vgbase = Vt + (size_t)(b * 4 + kvh) * 128 * 2048;

    for (int kt = 0; kt < nkt; ++kt) {
        __syncthreads();
        #pragma unroll
        for (int c = 0; c < 2; ++c) {
            const int chunk = 2 * w + c;
            const int lofs = chunk * 512 + lane * 8;
            __builtin_amdgcn_global_load_lds(AS1C(kgbase + (size_t)kt * 32 * 128 + lofs),
                                             AS3(&Ks[lofs]), 16, 0, 0);
            const int d_ = chunk * 16 + srow;
            __builtin_amdgcn_global_load_lds(AS1C(vgbase + (size_t)d_ * 2048 + kt * 32 + skc),
                                             AS3(&Vs[lofs]), 16, 0, 0);
        }
        __syncthreads();
        if (kt * 32 <= qw + 15) {   // wave-uniform causal skip
            f32x4 s0 = z, s1 = z;
            #pragma unroll
            for (int kk = 0; kk < 4; ++kk) {
                bf16x8 k0f = *(const bf16x8*)&Ks[lr * 128 + kk * 32 + quad * 8];
                bf16x8 k1f = *(const bf16x8*)&Ks[(16 + lr) * 128 + kk * 32 + quad * 8];
                s0 = MFMA_BF16(qf[kk], k0f, s0, 0, 0, 0);
                s1 = MFMA_BF16(qf[kk], k1f, s1, 0, 0, 0);
            }
            float p0[4], p1[4], mt[4];
            #pragma unroll
            for (int r = 0; r < 4; ++r) {
                int rg = qw + quad * 4 + r;
                int cg = kt * 32 + lr;
                float v0 = s0[r] * scale;
                float v1 = s1[r] * scale;
                if (cg > rg) v0 = -1e30f;
                if (cg + 16 > rg) v1 = -1e30f;
                p0[r] = v0; p1[r] = v1;
                mt[r] = fmaxf(v0, v1);
            }
            #pragma unroll
            for (int off = 1; off < 16; off <<= 1)
                #pragma unroll
                for (int r = 0; r < 4; ++r) mt[r] = fmaxf(mt[r], __shfl_xor(mt[r], off));
            float alpha[4], rsum[4];
            #pragma unroll
            for (int r = 0; r < 4; ++r) {
                float mn = fmaxf(m_r[r], mt[r]);
                alpha[r] = exp2f((m_r[r] - mn) * LOG2E);
                m_r[r] = mn;
                p0[r] = exp2f((p0[r] - mn) * LOG2E);
                p1[r] = exp2f((p1[r] - mn) * LOG2E);
                rsum[r] = p0[r] + p1[r];
            }
            #pragma unroll
            for (int off = 1; off < 16; off <<= 1)
                #pragma unroll
                for (int r = 0; r < 4; ++r) rsum[r] += __shfl_xor(rsum[r], off);
            #pragma unroll
            for (int r = 0; r < 4; ++r) l_r[r] = l_r[r] * alpha[r] + rsum[r];
            #pragma unroll
            for (int dt = 0; dt < 8; ++dt)
                #pragma unroll
                for (int r = 0; r < 4; ++r) o[dt][r] *= alpha[r];
            // P: C-layout -> A-layout via per-wave LDS
            u16* pw = &Ps[w][0];
            #pragma unroll
            for (int r = 0; r < 4; ++r) {
                pw[(quad * 4 + r) * 32 + lr]      = f2bf(p0[r]);
                pw[(quad * 4 + r) * 32 + 16 + lr] = f2bf(p1[r]);
            }
            bf16x8 pf = *(const bf16x8*)&pw[lr * 32 + quad * 8];
            #pragma unroll
            for (int dt = 0; dt < 8; ++dt) {
                bf16x8 vf = *(const bf16x8*)&Vs[(dt * 16 + lr) * 32 + quad * 8];
                o[dt] = MFMA_BF16(pf, vf, o[dt], 0, 0, 0);
            }
        }
    }
    float inv[4];
    #pragma unroll
    for (int r = 0; r < 4; ++r) inv[r] = 1.0f / l_r[r];
    #pragma unroll
    for (int dt = 0; dt < 8; ++dt)
        #pragma unroll
        for (int r = 0; r < 4; ++r) {
            int rg = qw + quad * 4 + r;
            size_t idx = ((size_t)b * 2048 + rg) * 2048 + h * 128 + dt * 16 + lr;
            O[idx] = f2bf(o[dt][r] * inv[r]);
        }
}

// ---------------- launch ----------------
extern "C" void kernel_launch(void* const* d_in, const int* in_sizes, int n_in,
                              void* d_out, int out_size, void* d_ws, size_t ws_size,
                              hipStream_t stream) {
    (void)in_sizes; (void)n_in; (void)out_size; (void)ws_size;
    const float* x    = (const float*)d_in[0];
    const float* fr   = (const float*)d_in[2];
    const float* wqkv = (const float*)d_in[4];
    const float* wfc  = (const float*)d_in[5];
    const float* w1   = (const float*)d_in[6];
    const float* w2   = (const float*)d_in[7];
    const float* w3   = (const float*)d_in[8];
    const float* anw  = (const float*)d_in[9];
    const float* fnw  = (const float*)d_in[10];
    float* out = (float*)d_out;
    char* ws = (char*)d_ws;
    size_t off = 0;
    auto alloc = [&](size_t bytes) -> void* {
        void* p = ws + off;
        off += (bytes + 255) & ~(size_t)255;
        return p;
    };
    u16*   wqkv_b = (u16*)alloc((size_t)3072 * 2048 * 2);
    u16*   wfc_b  = (u16*)alloc((size_t)2048 * 2048 * 2);
    u16*   w1_b   = (u16*)alloc((size_t)5632 * 2048 * 2);
    u16*   w2_b   = (u16*)alloc((size_t)5632 * 2048 * 2);
    u16*   w3_b   = (u16*)alloc((size_t)2048 * 5632 * 2);
    u16*   xn_b   = (u16*)alloc((size_t)4096 * 2048 * 2);    // reused as attn_b
    float* qkv_f  = (float*)alloc((size_t)4096 * 3072 * 4);  // reused as t_b
    u16*   q_b    = (u16*)alloc((size_t)4096 * 2048 * 2);    // reused as g_b
    u16*   k_b    = (u16*)alloc((size_t)4096 * 512 * 2);
    u16*   vt_b   = (u16*)alloc((size_t)4096 * 512 * 2);
    float* h_f    = (float*)alloc((size_t)4096 * 2048 * 4);
    u16* attn_b = xn_b;
    u16* t_b    = (u16*)qkv_f;
    u16* g_b    = q_b;

    cvt_kernel<<<6144, 256, 0, stream>>>(wqkv, wqkv_b, 3072 * 2048 / 4);
    cvt_kernel<<<4096, 256, 0, stream>>>(wfc, wfc_b, 2048 * 2048 / 4);
    cvt_kernel<<<11264, 256, 0, stream>>>(w1, w1_b, 5632 * 2048 / 4);
    cvt_kernel<<<11264, 256, 0, stream>>>(w2, w2_b, 5632 * 2048 / 4);
    cvt_kernel<<<11264, 256, 0, stream>>>(w3, w3_b, 2048 * 5632 / 4);

    rmsnorm_kernel<<<4096, 256, 0, stream>>>(x, anw, xn_b);
    gemm_bt<false, false><<<dim3(24, 32), 256, 0, stream>>>(
        xn_b, wqkv_b, nullptr, nullptr, qkv_f, nullptr, 4096, 3072, 2048);
    rope_kernel<<<4096, 256, 0, stream>>>(qkv_f, fr, q_b, k_b, vt_b);
    attn_kernel<<<dim3(32, 16, 2), 256, 0, stream>>>(q_b, k_b, vt_b, attn_b);
    gemm_bt<true, false><<<dim3(16, 32), 256, 0, stream>>>(
        attn_b, wfc_b, nullptr, x, h_f, nullptr, 4096, 2048, 2048);
    rmsnorm_kernel<<<4096, 256, 0, stream>>>(h_f, fnw, g_b);
    gemm_bt<false, true><<<dim3(44, 32), 256, 0, stream>>>(
        g_b, w1_b, w2_b, nullptr, nullptr, t_b, 4096, 5632, 2048);
    gemm_bt<true, false><<<dim3(16, 32), 256, 0, stream>>>(
        t_b, w3_b, nullptr, h_f, out, nullptr, 4096, 2048, 5632);
}

// Round 2
// 933.559 us; speedup vs baseline: 1.1337x; 1.1337x over previous
//
#include <hip/hip_runtime.h>
#include <cstdint>
#include <cstddef>

typedef unsigned short u16;
typedef short bf16x8 __attribute__((ext_vector_type(8)));
typedef float f32x4 __attribute__((ext_vector_type(4)));

#define AS1C(p) ((const __attribute__((address_space(1))) void*)(p))
#define AS3(p)  ((__attribute__((address_space(3))) void*)(p))
#define MFMA_BF16 __builtin_amdgcn_mfma_f32_16x16x32_bf16

__device__ __forceinline__ u16 f2bf(float f) {
    union { float f; unsigned int u; } v; v.f = f;
    unsigned int r = v.u + 0x7fffu + ((v.u >> 16) & 1u);
    return (u16)(r >> 16);
}

struct U16x4 { u16 x, y, z, w; };

// ---------------- fp32 -> bf16 weight conversion ----------------
__global__ __launch_bounds__(256) void cvt_kernel(const float* __restrict__ src,
                                                  u16* __restrict__ dst, int n4) {
    int i = blockIdx.x * 256 + threadIdx.x;
    if (i < n4) {
        const float4 v = ((const float4*)src)[i];
        U16x4 o; o.x = f2bf(v.x); o.y = f2bf(v.y); o.z = f2bf(v.z); o.w = f2bf(v.w);
        ((U16x4*)dst)[i] = o;
    }
}

// ---------------- RMSNorm (fp32 in, bf16 out), one block per token ----------------
__global__ __launch_bounds__(256) void rmsnorm_kernel(const float* __restrict__ X,
                                                      const float* __restrict__ W,
                                                      u16* __restrict__ Out) {
    const int row = blockIdx.x;
    const int t = threadIdx.x;
    const float* xr = X + (size_t)row * 2048;
    float4 a = ((const float4*)xr)[2 * t];
    float4 b = ((const float4*)xr)[2 * t + 1];
    float ss = a.x*a.x + a.y*a.y + a.z*a.z + a.w*a.w
             + b.x*b.x + b.y*b.y + b.z*b.z + b.w*b.w;
    #pragma unroll
    for (int off = 1; off < 64; off <<= 1) ss += __shfl_xor(ss, off);
    __shared__ float red[4];
    if ((t & 63) == 0) red[t >> 6] = ss;
    __syncthreads();
    float tot = red[0] + red[1] + red[2] + red[3];
    float rs = rsqrtf(tot * (1.0f / 2048.0f) + 1e-5f);
    float vals[8] = {a.x, a.y, a.z, a.w, b.x, b.y, b.z, b.w};
    const int base = t * 8;
    u16* orow = Out + (size_t)row * 2048 + base;
    #pragma unroll
    for (int j = 0; j < 8; ++j) orow[j] = f2bf(vals[j] * rs * W[base + j]);
}

// ---------------- RoPE split: qkv fp32 -> q,k (roped, bf16), v transposed bf16 ----------------
__global__ __launch_bounds__(256) void rope_kernel(const float* __restrict__ qkv,
                                                   const float* __restrict__ fr,
                                                   u16* __restrict__ Qo, u16* __restrict__ Ko,
                                                   u16* __restrict__ Vo) {
    const int tok = blockIdx.x;
    const int b = tok >> 11, s = tok & 2047;
    const int t = threadIdx.x;
    const float* row = qkv + (size_t)tok * 3072;
    const float* f = fr + (size_t)s * 128;
    #pragma unroll
    for (int i = 0; i < 4; ++i) {                 // 1024 q pairs
        int p = t + i * 256;
        int h = p >> 6, pi = p & 63;
        float x0 = row[h * 128 + pi * 2];
        float x1 = row[h * 128 + pi * 2 + 1];
        float c = f[pi * 2], sn = f[pi * 2 + 1];
        size_t ob = ((size_t)(b * 16 + h) * 2048 + s) * 128 + pi * 2;
        Qo[ob]     = f2bf(x0 * c - x1 * sn);
        Qo[ob + 1] = f2bf(x1 * c + x0 * sn);
    }
    {                                             // 256 k pairs
        int kh = t >> 6, pi = t & 63;
        float x0 = row[2048 + kh * 128 + pi * 2];
        float x1 = row[2048 + kh * 128 + pi * 2 + 1];
        float c = f[pi * 2], sn = f[pi * 2 + 1];
        size_t ob = ((size_t)(b * 4 + kh) * 2048 + s) * 128 + pi * 2;
        Ko[ob]     = f2bf(x0 * c - x1 * sn);
        Ko[ob + 1] = f2bf(x1 * c + x0 * sn);
    }
    #pragma unroll
    for (int i = 0; i < 2; ++i) {                 // 512 v elems, transposed (b,kv,d,s)
        int e = t + i * 256;
        int kh = e >> 7, d = e & 127;
        Vo[((size_t)(b * 4 + kh) * 128 + d) * 2048 + s] = f2bf(row[2560 + e]);
    }
}

// ---------------- GEMM: C(M,N) = A(M,K,bf16) * B(N,K,bf16)^T  [m97 structure] ----------------
template <bool RESID, bool DUAL>
__global__ __launch_bounds__(256, 2) void gemm_bt(
    const u16* __restrict__ A, const u16* __restrict__ B0, const u16* __restrict__ B1,
    const float* __restrict__ RES, float* __restrict__ Cf, u16* __restrict__ Cb,
    int M, int N, int K) {
    __shared__ __align__(16) u16 As[128 * 32];
    __shared__ __align__(16) u16 Bs[128 * 32];
    __shared__ __align__(16) u16 Bs2[128 * 32];
    const int w = threadIdx.x >> 6;
    const int lane = threadIdx.x & 63;
    const int bm = blockIdx.y * 128;
    const int bn = blockIdx.x * 128;
    const int wm = (w >> 1) * 64;
    const int wn = (w & 1) * 64;
    const int lr = lane & 15;
    const int kq = (lane >> 4) * 8;
    const int srow = lane >> 2;
    const int skc = (lane & 3) * 8;
    f32x4 acc[4][4];
    f32x4 acc2[4][4];
    const f32x4 z = {0.f, 0.f, 0.f, 0.f};
    #pragma unroll
    for (int i = 0; i < 4; ++i)
        #pragma unroll
        for (int j = 0; j < 4; ++j) { acc[i][j] = z; acc2[i][j] = z; }

    for (int k0 = 0; k0 < K; k0 += 32) {
        #pragma unroll
        for (int c = 0; c < 2; ++c) {
            const int chunk = 2 * w + c;
            const int r = chunk * 16 + srow;
            const int lofs = chunk * 512 + lane * 8;
            __builtin_amdgcn_global_load_lds(AS1C(A + (size_t)(bm + r) * K + k0 + skc),
                                             AS3(&As[lofs]), 16, 0, 0);
            __builtin_amdgcn_global_load_lds(AS1C(B0 + (size_t)(bn + r) * K + k0 + skc),
                                             AS3(&Bs[lofs]), 16, 0, 0);
            if constexpr (DUAL)
                __builtin_amdgcn_global_load_lds(AS1C(B1 + (size_t)(bn + r) * K + k0 + skc),
                                                 AS3(&Bs2[lofs]), 16, 0, 0);
        }
        __syncthreads();
        bf16x8 af[4], bfr[4];
        #pragma unroll
        for (int tm = 0; tm < 4; ++tm) af[tm] = *(const bf16x8*)&As[(wm + tm * 16 + lr) * 32 + kq];
        #pragma unroll
        for (int tn = 0; tn < 4; ++tn) bfr[tn] = *(const bf16x8*)&Bs[(wn + tn * 16 + lr) * 32 + kq];
        #pragma unroll
        for (int tm = 0; tm < 4; ++tm)
            #pragma unroll
            for (int tn = 0; tn < 4; ++tn)
                acc[tm][tn] = MFMA_BF16(af[tm], bfr[tn], acc[tm][tn], 0, 0, 0);
        if constexpr (DUAL) {
            #pragma unroll
            for (int tn = 0; tn < 4; ++tn) bfr[tn] = *(const bf16x8*)&Bs2[(wn + tn * 16 + lr) * 32 + kq];
            #pragma unroll
            for (int tm = 0; tm < 4; ++tm)
                #pragma unroll
                for (int tn = 0; tn < 4; ++tn)
                    acc2[tm][tn] = MFMA_BF16(af[tm], bfr[tn], acc2[tm][tn], 0, 0, 0);
        }
        __syncthreads();
    }
    #pragma unroll
    for (int tm = 0; tm < 4; ++tm) {
        const int row0 = bm + wm + tm * 16 + (lane >> 4) * 4;
        #pragma unroll
        for (int tn = 0; tn < 4; ++tn) {
            const int col = bn + wn + tn * 16 + (lane & 15);
            #pragma unroll
            for (int r = 0; r < 4; ++r) {
                const size_t idx = (size_t)(row0 + r) * N + col;
                if constexpr (DUAL) {
                    float aa = acc[tm][tn][r];
                    float bb = acc2[tm][tn][r];
                    float sg = aa / (1.0f + __expf(-aa));
                    Cb[idx] = f2bf(sg * bb);
                } else {
                    float v = acc[tm][tn][r];
                    if constexpr (RESID) v += RES[idx];
                    Cf[idx] = v;
                }
            }
        }
    }
}

// ---------------- Flash attention v2: BM=128 (wave=32 q-rows), BN=64 kv/iter ----------------
// LDS layouts built via per-lane-gather global_load_lds so fragment reads are
// bank-even:  Ks[dg][kv][8d] (dg=d/8),  Vs[slot][d&63][8s] (slot=(s/8)*2+(d/64)),
// Ps padded to stride 72 u16 (144 B, 16B-aligned, conflict-free A-frag reads).
__global__ __launch_bounds__(256, 2) void attn_kernel(
    const u16* __restrict__ Q, const u16* __restrict__ Kg,
    const u16* __restrict__ Vt, u16* __restrict__ O) {
    __shared__ __align__(16) u16 Ks[16 * 512];
    __shared__ __align__(16) u16 Vs[16 * 512];
    __shared__ __align__(16) u16 Ps[4][32 * 72];
    const int qt = (int)gridDim.x - 1 - (int)blockIdx.x;  // longest blocks first
    const int h = blockIdx.y, b = blockIdx.z;
    const int kvh = h >> 2;
    const int w = threadIdx.x >> 6, lane = threadIdx.x & 63;
    const int lr = lane & 15, quad = lane >> 4;
    const int q0 = qt * 128;
    const int wq = q0 + w * 32;              // wave's first q-row
    const u16* kgbase = Kg + (size_t)(b * 4 + kvh) * 2048 * 128;
    const u16* vgbase = Vt + (size_t)(b * 4 + kvh) * 128 * 2048;
    // Q fragments: A[m=lr][k=quad*8+j], rows wq+mt*16+lr
    bf16x8 qf[2][4];
    #pragma unroll
    for (int mt = 0; mt < 2; ++mt)
        #pragma unroll
        for (int kk = 0; kk < 4; ++kk)
            qf[mt][kk] = *(const bf16x8*)(Q + ((size_t)(b * 16 + h) * 2048 + wq + mt * 16 + lr) * 128
                                          + kk * 32 + quad * 8);
    f32x4 o[2][8];
    const f32x4 z = {0.f, 0.f, 0.f, 0.f};
    #pragma unroll
    for (int mt = 0; mt < 2; ++mt)
        #pragma unroll
        for (int dt = 0; dt < 8; ++dt) o[mt][dt] = z;
    float m_r[2][4], l_r[2][4];
    #pragma unroll
    for (int mt = 0; mt < 2; ++mt)
        #pragma unroll
        for (int r = 0; r < 4; ++r) { m_r[mt][r] = -1e30f; l_r[mt][r] = 0.f; }
    const float scale = 0.022097086912079608f;   // 1/sqrt(2048)
    const float LOG2E = 1.4426950408889634f;
    const int nkt = (q0 + 128) >> 6;

    for (int kt = 0; kt < nkt; ++kt) {
        __syncthreads();
        #pragma unroll
        for (int c = 0; c < 4; ++c) {
            const int i = w * 4 + c;             // 16 slots each for K and V
            // K: lane -> row kv=kt*64+lane, cols i*8..i*8+7
            __builtin_amdgcn_global_load_lds(
                AS1C(kgbase + (size_t)(kt * 64 + lane) * 128 + i * 8),
                AS3(&Ks[i * 512 + lane * 8]), 16, 0, 0);
            // V: lane -> d=(i&1)*64+lane, s = kt*64+(i>>1)*8 ..+7  (Vt row-contig in s)
            __builtin_amdgcn_global_load_lds(
                AS1C(vgbase + (size_t)((i & 1) * 64 + lane) * 2048 + kt * 64 + (i >> 1) * 8),
                AS3(&Vs[i * 512 + lane * 8]), 16, 0, 0);
        }
        __syncthreads();
        if (kt * 64 <= wq + 31) {                // wave-uniform causal skip
            f32x4 s[2][4];
            #pragma unroll
            for (int mt = 0; mt < 2; ++mt)
                #pragma unroll
                for (int nt = 0; nt < 4; ++nt) s[mt][nt] = z;
            #pragma unroll
            for (int kk = 0; kk < 4; ++kk) {
                bf16x8 kf[4];
                #pragma unroll
                for (int nt = 0; nt < 4; ++nt)
                    kf[nt] = *(const bf16x8*)&Ks[(kk * 4 + quad) * 512 + (nt * 16 + lr) * 8];
                #pragma unroll
                for (int mt = 0; mt < 2; ++mt)
                    #pragma unroll
                    for (int nt = 0; nt < 4; ++nt)
                        s[mt][nt] = MFMA_BF16(qf[mt][kk], kf[nt], s[mt][nt], 0, 0, 0);
            }
            u16* pw = &Ps[w][0];
            #pragma unroll
            for (int mt = 0; mt < 2; ++mt) {
                float mx[4];
                #pragma unroll
                for (int r = 0; r < 4; ++r) {
                    const int rg = wq + mt * 16 + quad * 4 + r;
                    float mm = -1e30f;
                    #pragma unroll
                    for (int nt = 0; nt < 4; ++nt) {
                        const int cg = kt * 64 + nt * 16 + lr;
                        float v = s[mt][nt][r] * scale;
                        if (cg > rg) v = -1e30f;
                        s[mt][nt][r] = v;
                        mm = fmaxf(mm, v);
                    }
                    mx[r] = mm;
                }
                #pragma unroll
                for (int off = 1; off < 16; off <<= 1)
                    #pragma unroll
                    for (int r = 0; r < 4; ++r) mx[r] = fmaxf(mx[r], __shfl_xor(mx[r], off));
                float rsum[4];
                #pragma unroll
                for (int r = 0; r < 4; ++r) {
                    const float mn = fmaxf(m_r[mt][r], mx[r]);
                    const float alpha = exp2f((m_r[mt][r] - mn) * LOG2E);
                    m_r[mt][r] = mn;
                    float rs = 0.f;
                    #pragma unroll
                    for (int nt = 0; nt < 4; ++nt) {
                        float p = exp2f((s[mt][nt][r] - mn) * LOG2E);
                        s[mt][nt][r] = p;
                        rs += p;
                    }
                    rsum[r] = rs;
                    l_r[mt][r] *= alpha;
                    #pragma unroll
                    for (int dt = 0; dt < 8; ++dt) o[mt][dt][r] *= alpha;
                }
                #pragma unroll
                for (int off = 1; off < 16; off <<= 1)
                    #pragma unroll
                    for (int r = 0; r < 4; ++r) rsum[r] += __shfl_xor(rsum[r], off);
                #pragma unroll
                for (int r = 0; r < 4; ++r) l_r[mt][r] += rsum[r];
                // P: C-layout -> LDS (stride 72)
                #pragma unroll
                for (int nt = 0; nt < 4; ++nt)
                    #pragma unroll
                    for (int r = 0; r < 4; ++r)
                        pw[(mt * 16 + quad * 4 + r) * 72 + nt * 16 + lr] = f2bf(s[mt][nt][r]);
            }
            // PV: P A-frags from padded LDS, V B-frags from bank-even Vs
            #pragma unroll
            for (int kf = 0; kf < 2; ++kf) {
                bf16x8 pf[2];
                #pragma unroll
                for (int mt = 0; mt < 2; ++mt)
                    pf[mt] = *(const bf16x8*)&pw[(mt * 16 + lr) * 72 + kf * 32 + quad * 8];
                #pragma unroll
                for (int dt = 0; dt < 8; ++dt) {
                    bf16x8 vf = *(const bf16x8*)&Vs[((kf * 4 + quad) * 2 + (dt >> 2)) * 512
                                                    + ((dt & 3) * 16 + lr) * 8];
                    #pragma unroll
                    for (int mt = 0; mt < 2; ++mt)
                        o[mt][dt] = MFMA_BF16(pf[mt], vf, o[mt][dt], 0, 0, 0);
                }
            }
        }
    }
    #pragma unroll
    for (int mt = 0; mt < 2; ++mt) {
        float inv[4];
        #pragma unroll
        for (int r = 0; r < 4; ++r) inv[r] = 1.0f / l_r[mt][r];
        #pragma unroll
        for (int dt = 0; dt < 8; ++dt)
            #pragma unroll
            for (int r = 0; r < 4; ++r) {
                const int rg = wq + mt * 16 + quad * 4 + r;
                const size_t idx = ((size_t)b * 2048 + rg) * 2048 + h * 128 + dt * 16 + lr;
                O[idx] = f2bf(o[mt][dt][r] * inv[r]);
            }
    }
}

// ---------------- launch ----------------
extern "C" void kernel_launch(void* const* d_in, const int* in_sizes, int n_in,
                              void* d_out, int out_size, void* d_ws, size_t ws_size,
                              hipStream_t stream) {
    (void)in_sizes; (void)n_in; (void)out_size; (void)ws_size;
    const float* x    = (const float*)d_in[0];
    const float* fr   = (const float*)d_in[2];
    const float* wqkv = (const float*)d_in[4];
    const float* wfc  = (const float*)d_in[5];
    const float* w1   = (const float*)d_in[6];
    const float* w2   = (const float*)d_in[7];
    const float* w3   = (const float*)d_in[8];
    const float* anw  = (const float*)d_in[9];
    const float* fnw  = (const float*)d_in[10];
    float* out = (float*)d_out;
    char* ws = (char*)d_ws;
    size_t off = 0;
    auto alloc = [&](size_t bytes) -> void* {
        void* p = ws + off;
        off += (bytes + 255) & ~(size_t)255;
        return p;
    };
    u16*   wqkv_b = (u16*)alloc((size_t)3072 * 2048 * 2);
    u16*   wfc_b  = (u16*)alloc((size_t)2048 * 2048 * 2);
    u16*   w1_b   = (u16*)alloc((size_t)5632 * 2048 * 2);
    u16*   w2_b   = (u16*)alloc((size_t)5632 * 2048 * 2);
    u16*   w3_b   = (u16*)alloc((size_t)2048 * 5632 * 2);
    u16*   xn_b   = (u16*)alloc((size_t)4096 * 2048 * 2);    // reused as attn_b
    float* qkv_f  = (float*)alloc((size_t)4096 * 3072 * 4);  // reused as t_b
    u16*   q_b    = (u16*)alloc((size_t)4096 * 2048 * 2);    // reused as g_b
    u16*   k_b    = (u16*)alloc((size_t)4096 * 512 * 2);
    u16*   vt_b   = (u16*)alloc((size_t)4096 * 512 * 2);
    float* h_f    = (float*)alloc((size_t)4096 * 2048 * 4);
    u16* attn_b = xn_b;
    u16* t_b    = (u16*)qkv_f;
    u16* g_b    = q_b;

    cvt_kernel<<<6144, 256, 0, stream>>>(wqkv, wqkv_b, 3072 * 2048 / 4);
    cvt_kernel<<<4096, 256, 0, stream>>>(wfc, wfc_b, 2048 * 2048 / 4);
    cvt_kernel<<<11264, 256, 0, stream>>>(w1, w1_b, 5632 * 2048 / 4);
    cvt_kernel<<<11264, 256, 0, stream>>>(w2, w2_b, 5632 * 2048 / 4);
    cvt_kernel<<<11264, 256, 0, stream>>>(w3, w3_b, 2048 * 5632 / 4);

    rmsnorm_kernel<<<4096, 256, 0, stream>>>(x, anw, xn_b);
    gemm_bt<false, false><<<dim3(24, 32), 256, 0, stream>>>(
        xn_b, wqkv_b, nullptr, nullptr, qkv_f, nullptr, 4096, 3072, 2048);
    rope_kernel<<<4096, 256, 0, stream>>>(qkv_f, fr, q_b, k_b, vt_b);
    attn_kernel<<<dim3(16, 16, 2), 256, 0, stream>>>(q_b, k_b, vt_b, attn_b);
    gemm_bt<true, false><<<dim3(16, 32), 256, 0, stream>>>(
        attn_b, wfc_b, nullptr, x, h_f, nullptr, 4096, 2048, 2048);
    rmsnorm_kernel<<<4096, 256, 0, stream>>>(h_f, fnw, g_b);
    gemm_bt<false, true><<<dim3(44, 32), 256, 0, stream>>>(
        g_b, w1_b, w2_b, nullptr, nullptr, t_b, 4096, 5632, 2048);
    gemm_bt<true, false><<<dim3(16, 32), 256, 0, stream>>>(
        t_b, w3_b, nullptr, h_f, out, nullptr, 4096, 2048, 5632);
}

// Round 3
// 854.768 us; speedup vs baseline: 1.2382x; 1.0922x over previous
//
#include <hip/hip_runtime.h>
#include <cstdint>
#include <cstddef>

typedef unsigned short u16;
typedef short bf16x8 __attribute__((ext_vector_type(8)));
typedef float f32x4 __attribute__((ext_vector_type(4)));

#define AS1C(p) ((const __attribute__((address_space(1))) void*)(p))
#define AS3(p)  ((__attribute__((address_space(3))) void*)(p))
#define MFMA_BF16 __builtin_amdgcn_mfma_f32_16x16x32_bf16

__device__ __forceinline__ u16 f2bf(float f) {
    union { float f; unsigned int u; } v; v.f = f;
    unsigned int r = v.u + 0x7fffu + ((v.u >> 16) & 1u);
    return (u16)(r >> 16);
}
__device__ __forceinline__ float bf2f(u16 u) {
    union { unsigned int i; float f; } v; v.i = ((unsigned int)u) << 16; return v.f;
}

struct U16x4 { u16 x, y, z, w; };

// ---------------- merged fp32 -> bf16 weight conversion (dst contiguous) ----------------
__global__ __launch_bounds__(256) void cvt_all(const float* __restrict__ s0,
                                               const float* __restrict__ s1,
                                               const float* __restrict__ s2,
                                               const float* __restrict__ s3,
                                               const float* __restrict__ s4,
                                               u16* __restrict__ dst) {
    const size_t i = (size_t)blockIdx.x * 256 + threadIdx.x;   // float4 index
    const float* src; size_t base;
    if      (i < 1572864u) { src = s0; base = 0; }             // w_qkv 3072*2048/4
    else if (i < 2621440u) { src = s1; base = 1572864u; }      // w_fc  2048*2048/4
    else if (i < 5505024u) { src = s2; base = 2621440u; }      // w1    5632*2048/4
    else if (i < 8388608u) { src = s3; base = 5505024u; }      // w2
    else                   { src = s4; base = 8388608u; }      // w3
    const float4 v = ((const float4*)src)[i - base];
    U16x4 o; o.x = f2bf(v.x); o.y = f2bf(v.y); o.z = f2bf(v.z); o.w = f2bf(v.w);
    ((U16x4*)dst)[i] = o;
}

// ---------------- RMSNorm (fp32 in, bf16 out), one block per token ----------------
__global__ __launch_bounds__(256) void rmsnorm_kernel(const float* __restrict__ X,
                                                      const float* __restrict__ W,
                                                      u16* __restrict__ Out) {
    const int row = blockIdx.x;
    const int t = threadIdx.x;
    const float* xr = X + (size_t)row * 2048;
    float4 a = ((const float4*)xr)[2 * t];
    float4 b = ((const float4*)xr)[2 * t + 1];
    float ss = a.x*a.x + a.y*a.y + a.z*a.z + a.w*a.w
             + b.x*b.x + b.y*b.y + b.z*b.z + b.w*b.w;
    #pragma unroll
    for (int off = 1; off < 64; off <<= 1) ss += __shfl_xor(ss, off);
    __shared__ float red[4];
    if ((t & 63) == 0) red[t >> 6] = ss;
    __syncthreads();
    float tot = red[0] + red[1] + red[2] + red[3];
    float rs = rsqrtf(tot * (1.0f / 2048.0f) + 1e-5f);
    float vals[8] = {a.x, a.y, a.z, a.w, b.x, b.y, b.z, b.w};
    const int base = t * 8;
    u16* orow = Out + (size_t)row * 2048 + base;
    #pragma unroll
    for (int j = 0; j < 8; ++j) orow[j] = f2bf(vals[j] * rs * W[base + j]);
}

// ---------------- RoPE split: qkv bf16 -> q,k (roped, bf16), v transposed bf16 ----------------
__global__ __launch_bounds__(256) void rope_kernel(const u16* __restrict__ qkv,
                                                   const float* __restrict__ fr,
                                                   u16* __restrict__ Qo, u16* __restrict__ Ko,
                                                   u16* __restrict__ Vo) {
    const int tok = blockIdx.x;
    const int b = tok >> 11, s = tok & 2047;
    const int t = threadIdx.x;
    const u16* row = qkv + (size_t)tok * 3072;
    const float* f = fr + (size_t)s * 128;
    #pragma unroll
    for (int i = 0; i < 4; ++i) {                 // 1024 q pairs
        int p = t + i * 256;
        int h = p >> 6, pi = p & 63;
        float x0 = bf2f(row[h * 128 + pi * 2]);
        float x1 = bf2f(row[h * 128 + pi * 2 + 1]);
        float c = f[pi * 2], sn = f[pi * 2 + 1];
        size_t ob = ((size_t)(b * 16 + h) * 2048 + s) * 128 + pi * 2;
        Qo[ob]     = f2bf(x0 * c - x1 * sn);
        Qo[ob + 1] = f2bf(x1 * c + x0 * sn);
    }
    {                                             // 256 k pairs
        int kh = t >> 6, pi = t & 63;
        float x0 = bf2f(row[2048 + kh * 128 + pi * 2]);
        float x1 = bf2f(row[2048 + kh * 128 + pi * 2 + 1]);
        float c = f[pi * 2], sn = f[pi * 2 + 1];
        size_t ob = ((size_t)(b * 4 + kh) * 2048 + s) * 128 + pi * 2;
        Ko[ob]     = f2bf(x0 * c - x1 * sn);
        Ko[ob + 1] = f2bf(x1 * c + x0 * sn);
    }
    #pragma unroll
    for (int i = 0; i < 2; ++i) {                 // 512 v elems, transposed (b,kv,d,s)
        int e = t + i * 256;
        int kh = e >> 7, d = e & 127;
        Vo[((size_t)(b * 4 + kh) * 128 + d) * 2048 + s] = row[2560 + e];
    }
}

// ---------------- GEMM BK=64: C(M,N) = A(M,K,bf16) * B(N,K,bf16)^T ----------------
// XOR-swizzled LDS (col-group ^= row&7) so BK=64 fragment reads are bank-even
// while global_load_lds dests stay lane-contiguous. 2 barriers per 64-K slab.
template <bool RESID, bool DUAL, bool BF16OUT>
__global__ __launch_bounds__(256, 2) void gemm_bt(
    const u16* __restrict__ A, const u16* __restrict__ B0, const u16* __restrict__ B1,
    const float* __restrict__ RES, float* __restrict__ Cf, u16* __restrict__ Cb,
    int M, int N, int K) {
    __shared__ __align__(16) u16 As[128 * 64];
    __shared__ __align__(16) u16 Bs[128 * 64];
    __shared__ __align__(16) u16 Bs2[DUAL ? 128 * 64 : 8];
    const int w = threadIdx.x >> 6;
    const int lane = threadIdx.x & 63;
    const int bm = blockIdx.y * 128;
    const int bn = blockIdx.x * 128;
    const int wm = (w >> 1) * 64;
    const int wn = (w & 1) * 64;
    const int lr = lane & 15;
    const int quad = lane >> 4;
    // staging lane map (per wave-instruction i): row = i*8 + lane/8,
    // global col-group = (lane&7) ^ ((lane>>3)&7), LDS dest = i*512 + lane*8
    const int srow = lane >> 3;
    const int sgc = ((lane & 7) ^ (srow & 7)) << 3;
    const int xq = lr & 7;                         // fragment-read xor key
    f32x4 acc[4][4];
    f32x4 acc2[DUAL ? 4 : 1][DUAL ? 4 : 1];
    const f32x4 z = {0.f, 0.f, 0.f, 0.f};
    #pragma unroll
    for (int i = 0; i < 4; ++i)
        #pragma unroll
        for (int j = 0; j < 4; ++j) acc[i][j] = z;
    if constexpr (DUAL) {
        #pragma unroll
        for (int i = 0; i < 4; ++i)
            #pragma unroll
            for (int j = 0; j < 4; ++j) acc2[i][j] = z;
    }

    for (int k0 = 0; k0 < K; k0 += 64) {
        #pragma unroll
        for (int c = 0; c < 4; ++c) {
            const int i = w * 4 + c;
            const int lofs = i * 512 + lane * 8;
            const int grow = i * 8 + srow;
            const size_t gofs = (size_t)grow * K + k0 + sgc;
            __builtin_amdgcn_global_load_lds(AS1C(A + (size_t)bm * K + gofs),
                                             AS3(&As[lofs]), 16, 0, 0);
            __builtin_amdgcn_global_load_lds(AS1C(B0 + (size_t)bn * K + gofs),
                                             AS3(&Bs[lofs]), 16, 0, 0);
            if constexpr (DUAL)
                __builtin_amdgcn_global_load_lds(AS1C(B1 + (size_t)bn * K + gofs),
                                                 AS3(&Bs2[lofs]), 16, 0, 0);
        }
        __syncthreads();
        #pragma unroll
        for (int kh = 0; kh < 2; ++kh) {
            const int slot = (((kh << 2) + quad) ^ xq) << 3;
            bf16x8 af[4], bfr[4];
            #pragma unroll
            for (int tm = 0; tm < 4; ++tm)
                af[tm] = *(const bf16x8*)&As[(wm + tm * 16 + lr) * 64 + slot];
            #pragma unroll
            for (int tn = 0; tn < 4; ++tn)
                bfr[tn] = *(const bf16x8*)&Bs[(wn + tn * 16 + lr) * 64 + slot];
            #pragma unroll
            for (int tm = 0; tm < 4; ++tm)
                #pragma unroll
                for (int tn = 0; tn < 4; ++tn)
                    acc[tm][tn] = MFMA_BF16(af[tm], bfr[tn], acc[tm][tn], 0, 0, 0);
            if constexpr (DUAL) {
                #pragma unroll
                for (int tn = 0; tn < 4; ++tn)
                    bfr[tn] = *(const bf16x8*)&Bs2[(wn + tn * 16 + lr) * 64 + slot];
                #pragma unroll
                for (int tm = 0; tm < 4; ++tm)
                    #pragma unroll
                    for (int tn = 0; tn < 4; ++tn)
                        acc2[tm][tn] = MFMA_BF16(af[tm], bfr[tn], acc2[tm][tn], 0, 0, 0);
            }
        }
        __syncthreads();
    }
    #pragma unroll
    for (int tm = 0; tm < 4; ++tm) {
        const int row0 = bm + wm + tm * 16 + (lane >> 4) * 4;
        #pragma unroll
        for (int tn = 0; tn < 4; ++tn) {
            const int col = bn + wn + tn * 16 + (lane & 15);
            #pragma unroll
            for (int r = 0; r < 4; ++r) {
                const size_t idx = (size_t)(row0 + r) * N + col;
                if constexpr (DUAL) {
                    float aa = acc[tm][tn][r];
                    float bb = acc2[tm][tn][r];
                    float sg = aa / (1.0f + __expf(-aa));
                    Cb[idx] = f2bf(sg * bb);
                } else if constexpr (BF16OUT) {
                    Cb[idx] = f2bf(acc[tm][tn][r]);
                } else {
                    float v = acc[tm][tn][r];
                    if constexpr (RESID) v += RES[idx];
                    Cf[idx] = v;
                }
            }
        }
    }
}

// ---------------- Flash attention: BM=128 (wave=32 q-rows), BN=64 kv/iter ----------------
__global__ __launch_bounds__(256, 2) void attn_kernel(
    const u16* __restrict__ Q, const u16* __restrict__ Kg,
    const u16* __restrict__ Vt, u16* __restrict__ O) {
    __shared__ __align__(16) u16 Ks[16 * 512];
    __shared__ __align__(16) u16 Vs[16 * 512];
    __shared__ __align__(16) u16 Ps[4][32 * 72];
    const int qt = (int)gridDim.x - 1 - (int)blockIdx.x;  // longest blocks first
    const int h = blockIdx.y, b = blockIdx.z;
    const int kvh = h >> 2;
    const int w = threadIdx.x >> 6, lane = threadIdx.x & 63;
    const int lr = lane & 15, quad = lane >> 4;
    const int q0 = qt * 128;
    const int wq = q0 + w * 32;
    const u16* kgbase = Kg + (size_t)(b * 4 + kvh) * 2048 * 128;
    const u16* vgbase = Vt + (size_t)(b * 4 + kvh) * 128 * 2048;
    bf16x8 qf[2][4];
    #pragma unroll
    for (int mt = 0; mt < 2; ++mt)
        #pragma unroll
        for (int kk = 0; kk < 4; ++kk)
            qf[mt][kk] = *(const bf16x8*)(Q + ((size_t)(b * 16 + h) * 2048 + wq + mt * 16 + lr) * 128
                                          + kk * 32 + quad * 8);
    f32x4 o[2][8];
    const f32x4 z = {0.f, 0.f, 0.f, 0.f};
    #pragma unroll
    for (int mt = 0; mt < 2; ++mt)
        #pragma unroll
        for (int dt = 0; dt < 8; ++dt) o[mt][dt] = z;
    float m_r[2][4], l_r[2][4];
    #pragma unroll
    for (int mt = 0; mt < 2; ++mt)
        #pragma unroll
        for (int r = 0; r < 4; ++r) { m_r[mt][r] = -1e30f; l_r[mt][r] = 0.f; }
    const float scale = 0.022097086912079608f;   // 1/sqrt(2048)
    const float LOG2E = 1.4426950408889634f;
    const int nkt = (q0 + 128) >> 6;

    for (int kt = 0; kt < nkt; ++kt) {
        __syncthreads();
        #pragma unroll
        for (int c = 0; c < 4; ++c) {
            const int i = w * 4 + c;
            __builtin_amdgcn_global_load_lds(
                AS1C(kgbase + (size_t)(kt * 64 + lane) * 128 + i * 8),
                AS3(&Ks[i * 512 + lane * 8]), 16, 0, 0);
            __builtin_amdgcn_global_load_lds(
                AS1C(vgbase + (size_t)((i & 1) * 64 + lane) * 2048 + kt * 64 + (i >> 1) * 8),
                AS3(&Vs[i * 512 + lane * 8]), 16, 0, 0);
        }
        __syncthreads();
        if (kt * 64 <= wq + 31) {
            f32x4 s[2][4];
            #pragma unroll
            for (int mt = 0; mt < 2; ++mt)
                #pragma unroll
                for (int nt = 0; nt < 4; ++nt) s[mt][nt] = z;
            #pragma unroll
            for (int kk = 0; kk < 4; ++kk) {
                bf16x8 kf[4];
                #pragma unroll
                for (int nt = 0; nt < 4; ++nt)
                    kf[nt] = *(const bf16x8*)&Ks[(kk * 4 + quad) * 512 + (nt * 16 + lr) * 8];
                #pragma unroll
                for (int mt = 0; mt < 2; ++mt)
                    #pragma unroll
                    for (int nt = 0; nt < 4; ++nt)
                        s[mt][nt] = MFMA_BF16(qf[mt][kk], kf[nt], s[mt][nt], 0, 0, 0);
            }
            u16* pw = &Ps[w][0];
            #pragma unroll
            for (int mt = 0; mt < 2; ++mt) {
                float mx[4];
                #pragma unroll
                for (int r = 0; r < 4; ++r) {
                    const int rg = wq + mt * 16 + quad * 4 + r;
                    float mm = -1e30f;
                    #pragma unroll
                    for (int nt = 0; nt < 4; ++nt) {
                        const int cg = kt * 64 + nt * 16 + lr;
                        float v = s[mt][nt][r] * scale;
                        if (cg > rg) v = -1e30f;
                        s[mt][nt][r] = v;
                        mm = fmaxf(mm, v);
                    }
                    mx[r] = mm;
                }
                #pragma unroll
                for (int off = 1; off < 16; off <<= 1)
                    #pragma unroll
                    for (int r = 0; r < 4; ++r) mx[r] = fmaxf(mx[r], __shfl_xor(mx[r], off));
                float rsum[4];
                #pragma unroll
                for (int r = 0; r < 4; ++r) {
                    const float mn = fmaxf(m_r[mt][r], mx[r]);
                    const float alpha = exp2f((m_r[mt][r] - mn) * LOG2E);
                    m_r[mt][r] = mn;
                    float rs = 0.f;
                    #pragma unroll
                    for (int nt = 0; nt < 4; ++nt) {
                        float p = exp2f((s[mt][nt][r] - mn) * LOG2E);
                        s[mt][nt][r] = p;
                        rs += p;
                    }
                    rsum[r] = rs;
                    l_r[mt][r] *= alpha;
                    #pragma unroll
                    for (int dt = 0; dt < 8; ++dt) o[mt][dt][r] *= alpha;
                }
                #pragma unroll
                for (int off = 1; off < 16; off <<= 1)
                    #pragma unroll
                    for (int r = 0; r < 4; ++r) rsum[r] += __shfl_xor(rsum[r], off);
                #pragma unroll
                for (int r = 0; r < 4; ++r) l_r[mt][r] += rsum[r];
                #pragma unroll
                for (int nt = 0; nt < 4; ++nt)
                    #pragma unroll
                    for (int r = 0; r < 4; ++r)
                        pw[(mt * 16 + quad * 4 + r) * 72 + nt * 16 + lr] = f2bf(s[mt][nt][r]);
            }
            #pragma unroll
            for (int kf = 0; kf < 2; ++kf) {
                bf16x8 pf[2];
                #pragma unroll
                for (int mt = 0; mt < 2; ++mt)
                    pf[mt] = *(const bf16x8*)&pw[(mt * 16 + lr) * 72 + kf * 32 + quad * 8];
                #pragma unroll
                for (int dt = 0; dt < 8; ++dt) {
                    bf16x8 vf = *(const bf16x8*)&Vs[((kf * 4 + quad) * 2 + (dt >> 2)) * 512
                                                    + ((dt & 3) * 16 + lr) * 8];
                    #pragma unroll
                    for (int mt = 0; mt < 2; ++mt)
                        o[mt][dt] = MFMA_BF16(pf[mt], vf, o[mt][dt], 0, 0, 0);
                }
            }
        }
    }
    #pragma unroll
    for (int mt = 0; mt < 2; ++mt) {
        float inv[4];
        #pragma unroll
        for (int r = 0; r < 4; ++r) inv[r] = 1.0f / l_r[mt][r];
        #pragma unroll
        for (int dt = 0; dt < 8; ++dt)
            #pragma unroll
            for (int r = 0; r < 4; ++r) {
                const int rg = wq + mt * 16 + quad * 4 + r;
                const size_t idx = ((size_t)b * 2048 + rg) * 2048 + h * 128 + dt * 16 + lr;
                O[idx] = f2bf(o[mt][dt][r] * inv[r]);
            }
    }
}

// ---------------- launch ----------------
extern "C" void kernel_launch(void* const* d_in, const int* in_sizes, int n_in,
                              void* d_out, int out_size, void* d_ws, size_t ws_size,
                              hipStream_t stream) {
    (void)in_sizes; (void)n_in; (void)out_size; (void)ws_size;
    const float* x    = (const float*)d_in[0];
    const float* fr   = (const float*)d_in[2];
    const float* wqkv = (const float*)d_in[4];
    const float* wfc  = (const float*)d_in[5];
    const float* w1   = (const float*)d_in[6];
    const float* w2   = (const float*)d_in[7];
    const float* w3   = (const float*)d_in[8];
    const float* anw  = (const float*)d_in[9];
    const float* fnw  = (const float*)d_in[10];
    float* out = (float*)d_out;
    char* ws = (char*)d_ws;
    size_t off = 0;
    auto alloc = [&](size_t bytes) -> void* {
        void* p = ws + off;
        off += (bytes + 255) & ~(size_t)255;
        return p;
    };
    // weights (contiguous, in cvt_all segment order)
    u16*   wqkv_b = (u16*)alloc((size_t)3072 * 2048 * 2);
    u16*   wfc_b  = (u16*)alloc((size_t)2048 * 2048 * 2);
    u16*   w1_b   = (u16*)alloc((size_t)5632 * 2048 * 2);
    u16*   w2_b   = (u16*)alloc((size_t)5632 * 2048 * 2);
    u16*   w3_b   = (u16*)alloc((size_t)2048 * 5632 * 2);
    u16*   xn_b   = (u16*)alloc((size_t)4096 * 2048 * 2);    // reused as attn_b
    u16*   t_b    = (u16*)alloc((size_t)4096 * 5632 * 2);    // reused as qkv_b
    u16*   q_b    = (u16*)alloc((size_t)4096 * 2048 * 2);    // reused as g_b
    u16*   k_b    = (u16*)alloc((size_t)4096 * 512 * 2);
    u16*   vt_b   = (u16*)alloc((size_t)4096 * 512 * 2);
    float* h_f    = (float*)alloc((size_t)4096 * 2048 * 4);
    u16* attn_b = xn_b;
    u16* qkv_b  = t_b;
    u16* g_b    = q_b;

    cvt_all<<<44032, 256, 0, stream>>>(wqkv, wfc, w1, w2, w3, wqkv_b);

    rmsnorm_kernel<<<4096, 256, 0, stream>>>(x, anw, xn_b);
    gemm_bt<false, false, true><<<dim3(24, 32), 256, 0, stream>>>(
        xn_b, wqkv_b, nullptr, nullptr, nullptr, qkv_b, 4096, 3072, 2048);
    rope_kernel<<<4096, 256, 0, stream>>>(qkv_b, fr, q_b, k_b, vt_b);
    attn_kernel<<<dim3(16, 16, 2), 256, 0, stream>>>(q_b, k_b, vt_b, attn_b);
    gemm_bt<true, false, false><<<dim3(16, 32), 256, 0, stream>>>(
        attn_b, wfc_b, nullptr, x, h_f, nullptr, 4096, 2048, 2048);
    rmsnorm_kernel<<<4096, 256, 0, stream>>>(h_f, fnw, g_b);
    gemm_bt<false, true, true><<<dim3(44, 32), 256, 0, stream>>>(
        g_b, w1_b, w2_b, nullptr, nullptr, t_b, 4096, 5632, 2048);
    gemm_bt<true, false, false><<<dim3(16, 32), 256, 0, stream>>>(
        t_b, w3_b, nullptr, h_f, out, nullptr, 4096, 2048, 5632);
}